// Round 1
// baseline (3662.584 us; speedup 1.0000x reference)
//
#include <hip/hip_runtime.h>

// ---------------- workspace layout (bytes) ----------------
// [0, 768)            : cross-block progress flags (3*64 ints), zeroed via hipMemsetAsync
// [1024, +297216)     : embW[c][tok][g]  = embed[c][tok] . Wih0[c][g][:64]      (3*258*96 f32)
// [.. , +258048)      : P[c][m][g][k]    7 folded/copied 96x32 matrices per ch  (3*7*96*32 f32)
// [.. , +8064)        : BI[c][s][g]      bias vectors (7 slots of 96 per ch)    (3*7*96 f32)
#define WS_EMBW_OFF 1024
#define WS_P_OFF    (WS_EMBW_OFF + 3*258*96*4)
#define WS_BI_OFF   (WS_P_OFF + 3*7*96*32*4)

#define DOT4(acc, v, wq) \
  acc = fmaf((v).w, (wq).w, fmaf((v).z, (wq).z, fmaf((v).y, (wq).y, fmaf((v).x, (wq).x, acc))))

__device__ __forceinline__ float fsig(float x) {
  x = fminf(fmaxf(x, -30.f), 30.f);
  return __fdividef(1.f, 1.f + __expf(-x));
}
__device__ __forceinline__ float ftanh(float x) {
  x = fminf(fmaxf(x, -15.f), 15.f);
  float e = __expf(-2.f * x);
  return __fdividef(1.f - e, 1.f + e);
}

// ---------------------------------------------------------------------------
// Precompute: embW table, folded matrices P (m0=Wc1=Wih0*Wh2e, m1=Wc2=Wih0*Wad,
// m2=Whh0, m3=Wih1, m4=Whh1, m5=Wih2, m6=Whh2), bias table BI.
// ---------------------------------------------------------------------------
__global__ void precompute_kernel(const float* __restrict__ embed, const float* __restrict__ Wih0,
                                  const float* __restrict__ Wihr, const float* __restrict__ Whh,
                                  const float* __restrict__ bih, const float* __restrict__ bhh,
                                  const float* __restrict__ Wh2e, const float* __restrict__ bh2e,
                                  const float* __restrict__ Wad, const float* __restrict__ bad,
                                  float* __restrict__ ws) {
  const int t = blockIdx.x * 256 + threadIdx.x;
  float* embW = (float*)((char*)ws + WS_EMBW_OFF);
  float* P    = (float*)((char*)ws + WS_P_OFF);
  float* BIv  = (float*)((char*)ws + WS_BI_OFF);
  const int N_EMBW = 3*258*96;
  const int N_P    = 3*7*96*32;
  const int N_BI   = 3*7*96;
  if (t < N_EMBW) {
    const int g = t % 96;
    const int tok = (t / 96) % 258;
    const int c = t / (96*258);
    const float* e = embed + (c*258 + tok)*64;
    const float* w = Wih0 + (c*96 + g)*65;
    float s = 0.f;
    for (int i = 0; i < 64; i++) s = fmaf(e[i], w[i], s);
    embW[t] = s;
  } else if (t < N_EMBW + N_P) {
    const int u = t - N_EMBW;
    const int k = u & 31;
    const int g = (u >> 5) % 96;
    const int mi = (u / (96*32)) % 7;
    const int c = u / (96*32*7);
    float v = 0.f;
    if (mi == 0) {
      const float* w = Wih0 + (c*96 + g)*65;
      const float* a = Wh2e + c*65*32;
      float s = 0.f;
      for (int e = 0; e < 65; e++) s = fmaf(w[e], a[e*32 + k], s);
      v = s;
    } else if (mi == 1) {
      if (c > 0) {
        const float* w = Wih0 + (c*96 + g)*65;
        const float* a = Wad + (c-1)*65*32;
        float s = 0.f;
        for (int e = 0; e < 65; e++) s = fmaf(w[e], a[e*32 + k], s);
        v = s;
      }
    } else if (mi == 2) v = Whh[((c*3 + 0)*96 + g)*32 + k];
    else if (mi == 3)   v = Wihr[((c*2 + 0)*96 + g)*32 + k];
    else if (mi == 4)   v = Whh[((c*3 + 1)*96 + g)*32 + k];
    else if (mi == 5)   v = Wihr[((c*2 + 1)*96 + g)*32 + k];
    else                v = Whh[((c*3 + 2)*96 + g)*32 + k];
    P[u] = v;
  } else if (t < N_EMBW + N_P + N_BI) {
    const int u = t - N_EMBW - N_P;
    const int g = u % 96;
    const int s = (u / 96) % 7;
    const int c = u / (96*7);
    float v = 0.f;
    if (s == 0) {
      float acc = bih[(c*3 + 0)*96 + g];
      const float* w = Wih0 + (c*96 + g)*65;
      const float* bb = bh2e + c*65;
      for (int e = 0; e < 65; e++) acc = fmaf(w[e], bb[e], acc);
      if (c > 0) {
        const float* ba = bad + (c-1)*65;
        for (int e = 0; e < 65; e++) acc = fmaf(w[e], ba[e], acc);
      }
      v = acc;
    }
    else if (s == 1) v = Wih0[(c*96 + g)*65 + 64];   // pos coefficient
    else if (s == 2) v = bhh[(c*3 + 0)*96 + g];
    else if (s == 3) v = bih[(c*3 + 1)*96 + g];
    else if (s == 4) v = bhh[(c*3 + 1)*96 + g];
    else if (s == 5) v = bih[(c*3 + 2)*96 + g];
    else             v = bhh[(c*3 + 2)*96 + g];
    BIv[u] = v;
  }
}

// ---------------------------------------------------------------------------
// Wavefront RNN. Grid: 192 blocks = (c = blockIdx>>6, b = blockIdx&63), 256 thr.
// Lane = (j = hidden idx 0..31, p = k-half). Wave w owns rows r ≡ w (mod 4).
// Anti-diagonal d = r + col, 127 diagonals. Channel c waits on channel c-1's
// per-diagonal flag (device-scope). Top-layer hidden is stored into d_out at
// [cell*258 + 0..32) and consumed by the projection kernel.
// ---------------------------------------------------------------------------
__launch_bounds__(256, 1)
__global__ void rnn_kernel(const int* __restrict__ x, float* __restrict__ ws,
                           float* __restrict__ out) {
  const int tid = threadIdx.x;
  const int lane = tid & 63;
  const int wv = tid >> 6;
  const int j = lane & 31;
  const int p = lane >> 5;
  const int b = blockIdx.x & 63;
  const int c = blockIdx.x >> 6;

  const float* __restrict__ embW = (const float*)((const char*)ws + WS_EMBW_OFF);
  const float* __restrict__ P    = (const float*)((const char*)ws + WS_P_OFF);
  const float* __restrict__ BI   = (const float*)((const char*)ws + WS_BI_OFF);
  int* flags = (int*)ws;

  __shared__ __align__(16) float h_state[64][3][32];   // per-row GRU state (3 layers)
  __shared__ __align__(16) float out_top[2][64][32];   // prev/cur diagonal top hidden
  __shared__ __align__(16) float po_stage[4][2][32];   // per-wave staged prev-channel out

  for (int i = tid; i < 64*3*32; i += 256) ((float*)h_state)[i] = 0.f;
  for (int i = tid; i < 4*2*32; i += 256) ((float*)po_stage)[i] = 0.f;

  // ---- load per-lane weights into registers (336 VGPRs) ----
  float4 W[7][3][4];
  {
    const float* Pc = P + c*(7*96*32);
#pragma unroll
    for (int m = 0; m < 7; m++) {
#pragma unroll
      for (int G = 0; G < 3; G++) {
        const float* row = Pc + (m*96 + G*32 + j)*32 + p*16;
#pragma unroll
        for (int q = 0; q < 4; q++) W[m][G][q] = ((const float4*)row)[q];
      }
    }
  }
  const float* BIc = BI + c*(7*96);
  const float b0r = BIc[j] + BIc[2*96 + j];
  const float b0z = BIc[32 + j] + BIc[2*96 + 32 + j];
  const float b0n = BIc[64 + j];
  const float bh0n = BIc[2*96 + 64 + j];
  const float w64r = BIc[96 + j], w64z = BIc[96 + 32 + j], w64n = BIc[96 + 64 + j];
  const float b1r = BIc[3*96 + j] + BIc[4*96 + j];
  const float b1z = BIc[3*96 + 32 + j] + BIc[4*96 + 32 + j];
  const float b1n = BIc[3*96 + 64 + j];
  const float bh1n = BIc[4*96 + 64 + j];
  const float b2r = BIc[5*96 + j] + BIc[6*96 + j];
  const float b2z = BIc[5*96 + 32 + j] + BIc[6*96 + 32 + j];
  const float b2n = BIc[5*96 + 64 + j];
  const float bh2n = BIc[6*96 + 64 + j];

  const int* xb = x + (b*3 + c)*4096;
  const size_t outbase_c  = ((size_t)(b*3 + c)) * 4096 * 258;
  const size_t outbase_pc = (c > 0) ? ((size_t)(b*3 + c - 1)) * 4096 * 258 : 0;

  __syncthreads();

  for (int d = 0; d < 127; d++) {
    if (c > 0 && tid == 0) {
      while (__hip_atomic_load(&flags[(c-1)*64 + b], __ATOMIC_ACQUIRE,
                               __HIP_MEMORY_SCOPE_AGENT) <= d)
        __builtin_amdgcn_s_sleep(4);
    }
    __syncthreads();

    const int r_lo = (d > 63) ? (d - 63) : 0;
    const int r_hi = (d < 63) ? d : 63;
    const int r0 = r_lo + ((wv - r_lo) & 3);
    const int m = (r0 <= r_hi) ? (((r_hi - r0) >> 2) + 1) : 0;

    if (m > 0) {
      // gather this wave's tokens for the diagonal
      int tokv = 0;
      if (lane < m) {
        int rl = r0 + 4*lane;
        tokv = xb[rl*64 + (d - rl)];
      }
      int tok0 = __builtin_amdgcn_readlane(tokv, 0);
      const float* eb0 = embW + (c*258 + tok0)*96;
      float ewr = eb0[j], ewz = eb0[32 + j], ewn = eb0[64 + j];
      float po_reg = 0.f;
      if (c > 0 && p == 0)
        po_reg = out[outbase_pc + ((size_t)(r0*64 + (d - r0)))*258 + j];

      for (int i = 0; i < m; i++) {
        const int rr = r0 + 4*i;
        const int jc = d - rr;
        if (c > 0 && p == 0) po_stage[wv][i & 1][j] = po_reg;
        // prefetch next cell's token-embedding row and prev-channel hidden
        float ewr_n = 0.f, ewz_n = 0.f, ewn_n = 0.f, po_n = 0.f;
        if (i + 1 < m) {
          int tokn = __builtin_amdgcn_readlane(tokv, i + 1);
          const float* ebn = embW + (c*258 + tokn)*96;
          ewr_n = ebn[j]; ewz_n = ebn[32 + j]; ewn_n = ebn[64 + j];
          if (c > 0 && p == 0) {
            int rr2 = rr + 4;
            po_n = out[outbase_pc + ((size_t)(rr2*64 + (d - rr2)))*258 + j];
          }
        }
        const float pos = (float)rr * 0.03125f - 1.0f;

        // ---------- layer 0 ----------
        float ar, az, an, ahn;
        if (p == 0) {
          ar = fmaf(pos, w64r, b0r) + ewr;
          az = fmaf(pos, w64z, b0z) + ewz;
          an = fmaf(pos, w64n, b0n) + ewn;
          ahn = bh0n;
        } else { ar = 0.f; az = 0.f; an = 0.f; ahn = 0.f; }
        {
          const float4* h4 = (const float4*)&h_state[rr][0][p*16];
#pragma unroll
          for (int q = 0; q < 4; q++) {
            float4 vh = h4[q];
            DOT4(ar, vh, W[2][0][q]);
            DOT4(az, vh, W[2][1][q]);
            DOT4(ahn, vh, W[2][2][q]);
          }
          if (rr > 0) {
            const float4* ph4 = (const float4*)&out_top[(d+1) & 1][rr-1][p*16];
#pragma unroll
            for (int q = 0; q < 4; q++) {
              float4 vp = ph4[q];
              DOT4(ar, vp, W[0][0][q]);
              DOT4(az, vp, W[0][1][q]);
              DOT4(an, vp, W[0][2][q]);
            }
          }
          if (c > 0) {
            const float4* po4 = (const float4*)&po_stage[wv][i & 1][p*16];
#pragma unroll
            for (int q = 0; q < 4; q++) {
              float4 vo = po4[q];
              DOT4(ar, vo, W[1][0][q]);
              DOT4(az, vo, W[1][1][q]);
              DOT4(an, vo, W[1][2][q]);
            }
          }
        }
        ar += __shfl_xor(ar, 32); az += __shfl_xor(az, 32);
        an += __shfl_xor(an, 32); ahn += __shfl_xor(ahn, 32);
        {
          float rg = fsig(ar), zg = fsig(az);
          float ng = ftanh(fmaf(rg, ahn, an));
          float hold = h_state[rr][0][j];
          float hn = fmaf(zg, hold - ng, ng);
          h_state[rr][0][j] = hn;
        }
        // ---------- layer 1 ----------
        if (p == 0) { ar = b1r; az = b1z; an = b1n; ahn = bh1n; }
        else { ar = 0.f; az = 0.f; an = 0.f; ahn = 0.f; }
        {
          const float4* in4 = (const float4*)&h_state[rr][0][p*16];
          const float4* h4  = (const float4*)&h_state[rr][1][p*16];
#pragma unroll
          for (int q = 0; q < 4; q++) {
            float4 vi = in4[q];
            float4 vh = h4[q];
            DOT4(ar, vi, W[3][0][q]);
            DOT4(az, vi, W[3][1][q]);
            DOT4(an, vi, W[3][2][q]);
            DOT4(ar, vh, W[4][0][q]);
            DOT4(az, vh, W[4][1][q]);
            DOT4(ahn, vh, W[4][2][q]);
          }
        }
        ar += __shfl_xor(ar, 32); az += __shfl_xor(az, 32);
        an += __shfl_xor(an, 32); ahn += __shfl_xor(ahn, 32);
        {
          float rg = fsig(ar), zg = fsig(az);
          float ng = ftanh(fmaf(rg, ahn, an));
          float hold = h_state[rr][1][j];
          float hn = fmaf(zg, hold - ng, ng);
          h_state[rr][1][j] = hn;
        }
        // ---------- layer 2 ----------
        if (p == 0) { ar = b2r; az = b2z; an = b2n; ahn = bh2n; }
        else { ar = 0.f; az = 0.f; an = 0.f; ahn = 0.f; }
        {
          const float4* in4 = (const float4*)&h_state[rr][1][p*16];
          const float4* h4  = (const float4*)&h_state[rr][2][p*16];
#pragma unroll
          for (int q = 0; q < 4; q++) {
            float4 vi = in4[q];
            float4 vh = h4[q];
            DOT4(ar, vi, W[5][0][q]);
            DOT4(az, vi, W[5][1][q]);
            DOT4(an, vi, W[5][2][q]);
            DOT4(ar, vh, W[6][0][q]);
            DOT4(az, vh, W[6][1][q]);
            DOT4(ahn, vh, W[6][2][q]);
          }
        }
        ar += __shfl_xor(ar, 32); az += __shfl_xor(az, 32);
        an += __shfl_xor(an, 32); ahn += __shfl_xor(ahn, 32);
        {
          float rg = fsig(ar), zg = fsig(az);
          float ng = ftanh(fmaf(rg, ahn, an));
          float hold = h_state[rr][2][j];
          float hn = fmaf(zg, hold - ng, ng);
          h_state[rr][2][j] = hn;
          if (p == 0) {
            out_top[d & 1][rr][j] = hn;
            out[outbase_c + ((size_t)(rr*64 + jc))*258 + j] = hn;  // stash hidden
          }
        }
        ewr = ewr_n; ewz = ewz_n; ewn = ewn_n; po_reg = po_n;
      }
    }
    __syncthreads();
    if (c < 2 && tid == 0) {
      __threadfence();
      __hip_atomic_store(&flags[c*64 + b], d + 1, __ATOMIC_RELEASE,
                         __HIP_MEMORY_SCOPE_AGENT);
    }
  }
}

// ---------------------------------------------------------------------------
// Projection: out[cell][v] = hid[cell] . W_out[v] + b_out[v].
// Hidden rows live at out[cell*258 + 0..32); each block stages its own 32
// cells into LDS, then overwrites. v = tid (0..255), tail v=256,257 by wave 0.
// ---------------------------------------------------------------------------
__launch_bounds__(256, 2)
__global__ void proj_kernel(const float* __restrict__ Wout, const float* __restrict__ bout,
                            float* __restrict__ out) {
  __shared__ __align__(16) float hl[32*32];
  const int tid = threadIdx.x;
  const size_t base = (size_t)blockIdx.x * 32 * 258;

  for (int i = tid; i < 1024; i += 256) {
    int cell = i >> 5, k = i & 31;
    hl[i] = out[base + (size_t)cell*258 + k];
  }
  __syncthreads();

  float4 wr[8];
  {
    const float* wp = Wout + tid*32;
#pragma unroll
    for (int q = 0; q < 8; q++) wr[q] = ((const float4*)wp)[q];
  }
  const float bb = bout[tid];
  for (int cell = 0; cell < 32; cell++) {
    const float4* hv = (const float4*)&hl[cell*32];
    float acc = bb;
#pragma unroll
    for (int q = 0; q < 8; q++) {
      float4 h4 = hv[q];
      DOT4(acc, h4, wr[q]);
    }
    out[base + (size_t)cell*258 + tid] = acc;
  }
  if (tid < 64) {
    int cell = tid >> 1;
    int vv = 256 + (tid & 1);
    float acc = bout[vv];
    const float* wp = Wout + vv*32;
    const float* hp = &hl[cell*32];
#pragma unroll
    for (int k = 0; k < 32; k++) acc = fmaf(hp[k], wp[k], acc);
    out[base + (size_t)cell*258 + vv] = acc;
  }
}

extern "C" void kernel_launch(void* const* d_in, const int* in_sizes, int n_in,
                              void* d_out, int out_size, void* d_ws, size_t ws_size,
                              hipStream_t stream) {
  (void)in_sizes; (void)n_in; (void)out_size; (void)ws_size;
  const int*   x     = (const int*)  d_in[0];
  const float* embed = (const float*)d_in[1];
  const float* Wih0  = (const float*)d_in[2];
  const float* Wihr  = (const float*)d_in[3];
  const float* Whh   = (const float*)d_in[4];
  const float* bih   = (const float*)d_in[5];
  const float* bhh   = (const float*)d_in[6];
  const float* Wh2e  = (const float*)d_in[7];
  const float* bh2e  = (const float*)d_in[8];
  const float* Wad   = (const float*)d_in[9];
  const float* bad   = (const float*)d_in[10];
  const float* Wout  = (const float*)d_in[11];
  const float* bout  = (const float*)d_in[12];
  float* out = (float*)d_out;
  float* ws  = (float*)d_ws;

  hipMemsetAsync(d_ws, 0, 1024, stream);  // zero cross-block flags
  precompute_kernel<<<551, 256, 0, stream>>>(embed, Wih0, Wihr, Whh, bih, bhh,
                                             Wh2e, bh2e, Wad, bad, ws);
  rnn_kernel<<<192, 256, 0, stream>>>(x, ws, out);
  proj_kernel<<<24576, 256, 0, stream>>>(Wout, bout, out);
}